// Round 8
// baseline (215.213 us; speedup 1.0000x reference)
//
#include <hip/hip_runtime.h>
#include <hip/hip_bf16.h>

#define NHEAD 2
#define CDIM  64
#define HC    128
#define HID   256
#define BCOLS 1024
#define NXCD  8

// Fixed-point pack: one u64 per (node, head):
//   hi32 = den in 16.16; lo32 = num' in 12.20, num' = ex*(xs+KOFF) > 0.
// Positive fields => low->high carry impossible; integer adds exact &
// order-invariant => bit-deterministic accumulation (replica folding too).
#define KOFF 8.0f

// ---------------------------------------------------------------------------
// Kernel A: per-edge logits + ONE packed u64 atomic per (edge, head), into
// the XCD-LOCAL replica (replica id = physical XCC_ID). All writers of a
// replica share that XCD's L2 -> workgroup-scope (L2-local) atomics suffice;
// kernel-end L2 writeback publishes them to the folding kernel.
// ---------------------------------------------------------------------------
__global__ __launch_bounds__(256) void edge_kernel(
    const float* __restrict__ x,
    const int* __restrict__ ei,         // [2][E] int32
    const float* __restrict__ ea,
    const float* __restrict__ Wl, const float* __restrict__ bl,
    const float* __restrict__ Wr, const float* __restrict__ br,
    const float* __restrict__ We, const float* __restrict__ att,
    unsigned long long* __restrict__ rep,    // [NXCD][N*2] packed
    int E, int n2)
{
    __shared__ float swl[HC], swr[HC], swe[HC], sat[HC], sbs[HC];
    int t = threadIdx.x;
    if (t < HC) {
        swl[t] = Wl[t]; swr[t] = Wr[t]; swe[t] = We[t];
        sat[t] = att[t]; sbs[t] = bl[t] + br[t];
    }
    __syncthreads();
    int e = blockIdx.x * 256 + t;
    if (e >= E) return;

    unsigned int xcc;
    asm volatile("s_getreg_b32 %0, hwreg(HW_REG_XCC_ID)" : "=s"(xcc));
    unsigned long long* my = rep + (size_t)(xcc & (NXCD - 1)) * n2;

    int src = ei[e], dst = ei[E + e];
    float xs = x[src], xd = x[dst], a = ea[e];
    float l0 = 0.f, l1 = 0.f;
    #pragma unroll
    for (int c = 0; c < CDIM; ++c) {
        float v = fmaf(xs, swl[c], fmaf(xd, swr[c], fmaf(a, swe[c], sbs[c])));
        v = v > 0.f ? v : 0.2f * v;
        l0 = fmaf(v, sat[c], l0);
    }
    #pragma unroll
    for (int c = CDIM; c < HC; ++c) {
        float v = fmaf(xs, swl[c], fmaf(xd, swr[c], fmaf(a, swe[c], sbs[c])));
        v = v > 0.f ? v : 0.2f * v;
        l1 = fmaf(v, sat[c], l1);
    }
    float ex0 = __expf(l0), ex1 = __expf(l1);
    float w = xs + KOFF;                      // > 0
    unsigned long long p0 =
        ((unsigned long long)(ex0 * 65536.0f + 0.5f) << 32) +
        (unsigned long long)(ex0 * w * 1048576.0f + 0.5f);
    unsigned long long p1 =
        ((unsigned long long)(ex1 * 65536.0f + 0.5f) << 32) +
        (unsigned long long)(ex1 * w * 1048576.0f + 0.5f);
    __hip_atomic_fetch_add(&my[dst * 2 + 0], p0,
                           __ATOMIC_RELAXED, __HIP_MEMORY_SCOPE_WORKGROUP);
    __hip_atomic_fetch_add(&my[dst * 2 + 1], p1,
                           __ATOMIC_RELAXED, __HIP_MEMORY_SCOPE_WORKGROUP);
}

// ---------------------------------------------------------------------------
// Kernel A2: fold NXCD replicas -> accP[(node,head)]. Integer adds: exact,
// order-invariant => deterministic regardless of workgroup->XCD placement.
// ---------------------------------------------------------------------------
__global__ __launch_bounds__(256) void reduce_rep(
    const unsigned long long* __restrict__ rep,
    unsigned long long* __restrict__ accP, int n2)
{
    int i = blockIdx.x * 256 + threadIdx.x;
    if (i >= n2) return;
    unsigned long long s = 0ULL;
    #pragma unroll
    for (int r = 0; r < NXCD; ++r) s += rep[(size_t)r * n2 + i];
    accP[i] = s;
}

// ---------------------------------------------------------------------------
// Kernel B: me[b] = fc_b + fcW . msg[b], reduced to the FIVE rank factors:
//   y[0][b]=<Wl[0:64],me_b>  y[1][b]=<Wl[64:128],me_b>
//   y[2][b]=<bl[0:64],me_b>  y[3][b]=<bl[64:128],me_b>  y[4][b]=<bias_out,me_b>
// (dots = S0*y0 + S1*y1 + T0*y2 + T1*y3 + y4 — exact rank-5 factorization.)
// ---------------------------------------------------------------------------
__global__ __launch_bounds__(128) void me_y_kernel(
    const float* __restrict__ message, const float* __restrict__ fcW,
    const float* __restrict__ fcb,
    const float* __restrict__ Wl, const float* __restrict__ bl,
    const float* __restrict__ bias_out,
    float* __restrict__ y)              // [5][BCOLS]
{
    __shared__ float msg[HID];
    __shared__ float part[3][2];        // [term][head-wave]
    int b = blockIdx.x, t = threadIdx.x;
    msg[t]       = message[b * HID + t];
    msg[t + 128] = message[b * HID + 128 + t];
    __syncthreads();
    float acc = fcb[t];
    const float4* w4 = (const float4*)(fcW + t * HID);
    const float4* m4 = (const float4*)msg;
    #pragma unroll
    for (int q = 0; q < HID / 4; ++q) {
        float4 w = w4[q], m = m4[q];
        acc = fmaf(w.x, m.x, fmaf(w.y, m.y, fmaf(w.z, m.z, fmaf(w.w, m.w, acc))));
    }
    float p0 = Wl[t] * acc, p1 = bl[t] * acc, p2 = bias_out[t] * acc;
    #pragma unroll
    for (int d = 1; d < 64; d <<= 1) {
        p0 += __shfl_xor(p0, d); p1 += __shfl_xor(p1, d); p2 += __shfl_xor(p2, d);
    }
    int wv = t >> 6;
    if ((t & 63) == 0) { part[0][wv] = p0; part[1][wv] = p1; part[2][wv] = p2; }
    __syncthreads();
    if (t == 0) {
        y[0 * BCOLS + b] = part[0][0];
        y[1 * BCOLS + b] = part[0][1];
        y[2 * BCOLS + b] = part[1][0];
        y[3 * BCOLS + b] = part[1][1];
        y[4 * BCOLS + b] = part[2][0] + part[2][1];
    }
}

// ---------------------------------------------------------------------------
// Kernel C: per node row: decode (S,T) per head, logits = rank-5 combine,
// exp, wave-reduce sum, normalized write. One wave per row, 16 cols/lane.
// Write-bound: 200 MB coalesced float4 stores.
// ---------------------------------------------------------------------------
__global__ __launch_bounds__(256) void row_softmax_kernel(
    const unsigned long long* __restrict__ accP,   // [N][2]
    const float* __restrict__ y,                   // [5][BCOLS]
    float* __restrict__ out, int N)
{
    __shared__ float ys[5][BCOLS];      // 20 KB
    int t = threadIdx.x;
    for (int r = t; r < 5 * BCOLS; r += 256)
        ((float*)ys)[r] = y[r];
    __syncthreads();

    int wv = t >> 6, ln = t & 63;
    int node = blockIdx.x * 4 + wv;
    if (node >= N) return;

    unsigned long long v0 = accP[node * 2 + 0];
    unsigned long long v1 = accP[node * 2 + 1];
    float S0 = 0.f, T0 = 0.f, S1 = 0.f, T1 = 0.f;
    if (v0 != 0ULL) {
        double den  = (double)(v0 >> 32) * (1.0 / 65536.0);
        double nump = (double)(v0 & 0xffffffffULL) * (1.0 / 1048576.0);
        S0 = (float)((nump - (double)KOFF * den) / den);
        T0 = (float)(den / (den + 1e-16));
    }
    if (v1 != 0ULL) {
        double den  = (double)(v1 >> 32) * (1.0 / 65536.0);
        double nump = (double)(v1 & 0xffffffffULL) * (1.0 / 1048576.0);
        S1 = (float)((nump - (double)KOFF * den) / den);
        T1 = (float)(den / (den + 1e-16));
    }

    float e[16];
    float sum = 0.f;
    #pragma unroll
    for (int u = 0; u < 4; ++u) {
        int c = ln * 4 + u * 256;
        float4 a  = *(const float4*)&ys[0][c];
        float4 b2 = *(const float4*)&ys[1][c];
        float4 c2 = *(const float4*)&ys[2][c];
        float4 d2 = *(const float4*)&ys[3][c];
        float4 k2 = *(const float4*)&ys[4][c];
        float lx = fmaf(S0, a.x, fmaf(S1, b2.x, fmaf(T0, c2.x, fmaf(T1, d2.x, k2.x))));
        float ly = fmaf(S0, a.y, fmaf(S1, b2.y, fmaf(T0, c2.y, fmaf(T1, d2.y, k2.y))));
        float lz = fmaf(S0, a.z, fmaf(S1, b2.z, fmaf(T0, c2.z, fmaf(T1, d2.z, k2.z))));
        float lw = fmaf(S0, a.w, fmaf(S1, b2.w, fmaf(T0, c2.w, fmaf(T1, d2.w, k2.w))));
        e[u * 4 + 0] = __expf(lx); e[u * 4 + 1] = __expf(ly);
        e[u * 4 + 2] = __expf(lz); e[u * 4 + 3] = __expf(lw);
        sum += e[u * 4 + 0] + e[u * 4 + 1] + e[u * 4 + 2] + e[u * 4 + 3];
    }
    #pragma unroll
    for (int d = 1; d < 64; d <<= 1) sum += __shfl_xor(sum, d);
    float inv = 1.f / sum;

    float* orow = out + (size_t)node * BCOLS;
    #pragma unroll
    for (int u = 0; u < 4; ++u) {
        float4 o = make_float4(e[u * 4 + 0] * inv, e[u * 4 + 1] * inv,
                               e[u * 4 + 2] * inv, e[u * 4 + 3] * inv);
        *(float4*)(orow + ln * 4 + u * 256) = o;
    }
}

extern "C" void kernel_launch(void* const* d_in, const int* in_sizes, int n_in,
                              void* d_out, int out_size, void* d_ws, size_t ws_size,
                              hipStream_t stream) {
    const float* x        = (const float*)d_in[0];
    const int*   ei       = (const int*)d_in[1];
    const float* ea       = (const float*)d_in[2];
    const float* message  = (const float*)d_in[3];
    const float* Wl       = (const float*)d_in[4];
    const float* bl       = (const float*)d_in[5];
    const float* Wr       = (const float*)d_in[6];
    const float* br       = (const float*)d_in[7];
    const float* We       = (const float*)d_in[8];
    const float* att      = (const float*)d_in[9];
    const float* bias_out = (const float*)d_in[10];
    const float* fcW      = (const float*)d_in[11];
    const float* fcb      = (const float*)d_in[12];

    int N = in_sizes[0];          // 50000
    int E = in_sizes[2];          // 1600000
    int B = in_sizes[3] / HID;    // 1024
    int n2 = N * 2;

    // ws: accP u64[N*2] (800 KB) + y f32[5*BCOLS] (20 KB)
    unsigned long long* accP = (unsigned long long*)d_ws;
    float* y = (float*)(accP + (size_t)n2);

    // d_out doubles as replica scratch (fully overwritten by row_softmax).
    unsigned long long* rep = (unsigned long long*)d_out;  // [NXCD][N*2]

    hipMemsetAsync(rep, 0, sizeof(unsigned long long) * (size_t)NXCD * n2, stream);
    me_y_kernel<<<B, 128, 0, stream>>>(message, fcW, fcb, Wl, bl, bias_out, y);
    edge_kernel<<<(E + 255) / 256, 256, 0, stream>>>(x, ei, ea, Wl, bl, Wr, br, We, att,
                                                     rep, E, n2);
    reduce_rep<<<(n2 + 255) / 256, 256, 0, stream>>>(rep, accP, n2);
    row_softmax_kernel<<<(N + 3) / 4, 256, 0, stream>>>(accP, y, (float*)d_out, N);
}

// Round 9
// 199.260 us; speedup vs baseline: 1.0801x; 1.0801x over previous
//
#include <hip/hip_runtime.h>
#include <hip/hip_bf16.h>

#define NHEAD 2
#define CDIM  64
#define HC    128
#define HID   256
#define BCOLS 1024
#define CHUNK 2048     // edges per block in count/scatter
#define BSH   7        // bucket = dst >> BSH
#define BNODES 128     // nodes per bucket (1 << BSH)
#define MAXBUCK 512    // LDS sizing (nbuck = ceil(N/128) = 391 for N=50000)

// Fixed-point fields (independent u32 accumulators -> exact, order-invariant):
//   den: 16.16  (sum <= ~maxdeg*20*2^16 << 2^32)
//   num: 12.20  num' = ex*(xs+KOFF) > 0 (sum < 2^32; same margins as rounds 6-8)
#define KOFF 8.0f

// ---------------------------------------------------------------------------
// Pass 1: per-block histogram of dst buckets.
// ---------------------------------------------------------------------------
__global__ __launch_bounds__(256) void count_kernel(
    const int* __restrict__ ei, unsigned* __restrict__ counts,
    int E, int nblk, int nbuck)
{
    __shared__ unsigned hist[MAXBUCK];
    int t = threadIdx.x, b = blockIdx.x;
    for (int i = t; i < nbuck; i += 256) hist[i] = 0;
    __syncthreads();
    int start = b * CHUNK;
    #pragma unroll
    for (int u = 0; u < CHUNK / 256; ++u) {
        int e = start + u * 256 + t;
        if (e < E) atomicAdd(&hist[((unsigned)ei[E + e]) >> BSH], 1u);
    }
    __syncthreads();
    for (int i = t; i < nbuck; i += 256) counts[(size_t)i * nblk + b] = hist[i];
}

// ---------------------------------------------------------------------------
// Pass 2a: per bucket, exclusive prefix over blocks -> off[bucket][blk],
// plus totals[bucket]. One wave per bucket, shfl-based scan.
// ---------------------------------------------------------------------------
__global__ __launch_bounds__(64) void scan_bucket_kernel(
    const unsigned* __restrict__ counts, unsigned* __restrict__ off,
    unsigned* __restrict__ totals, int nblk)
{
    int bk = blockIdx.x, ln = threadIdx.x;
    const unsigned* c = counts + (size_t)bk * nblk;
    unsigned* o = off + (size_t)bk * nblk;
    unsigned running = 0;
    for (int b0 = 0; b0 < nblk; b0 += 64) {
        int i = b0 + ln;
        unsigned v = (i < nblk) ? c[i] : 0u;
        unsigned s = v;
        #pragma unroll
        for (int d = 1; d < 64; d <<= 1) {
            unsigned p = __shfl_up(s, d);
            if (ln >= d) s += p;
        }
        if (i < nblk) o[i] = running + s - v;
        running += __shfl(s, 63);
    }
    if (ln == 0) totals[bk] = running;
}

// ---------------------------------------------------------------------------
// Pass 2b: exclusive scan of bucket totals -> base[bucket]. Single wave.
// ---------------------------------------------------------------------------
__global__ __launch_bounds__(64) void scan_base_kernel(
    const unsigned* __restrict__ totals, unsigned* __restrict__ base, int nbuck)
{
    int ln = threadIdx.x;
    unsigned running = 0;
    for (int b0 = 0; b0 < nbuck; b0 += 64) {
        int i = b0 + ln;
        unsigned v = (i < nbuck) ? totals[i] : 0u;
        unsigned s = v;
        #pragma unroll
        for (int d = 1; d < 64; d <<= 1) {
            unsigned p = __shfl_up(s, d);
            if (ln >= d) s += p;
        }
        if (i < nbuck) base[i] = running + s - v;
        running += __shfl(s, 63);
    }
}

// ---------------------------------------------------------------------------
// Pass 3: recompute edge logits, pack 4 fixed-point fields, scatter payload
// to its bucket run (position via LDS cursor; any order within a run is fine:
// pass 4 sums are order-invariant integers).
// ---------------------------------------------------------------------------
__global__ __launch_bounds__(256) void scatter_kernel(
    const float* __restrict__ x,
    const int* __restrict__ ei,
    const float* __restrict__ ea,
    const float* __restrict__ Wl, const float* __restrict__ bl,
    const float* __restrict__ Wr, const float* __restrict__ br,
    const float* __restrict__ We, const float* __restrict__ att,
    const unsigned* __restrict__ off, const unsigned* __restrict__ base,
    uint4* __restrict__ payA, unsigned* __restrict__ payD,
    int E, int nblk, int nbuck)
{
    __shared__ float swl[HC], swr[HC], swe[HC], sat[HC], sbs[HC];
    __shared__ unsigned cursor[MAXBUCK];
    int t = threadIdx.x, b = blockIdx.x;
    if (t < HC) {
        swl[t] = Wl[t]; swr[t] = Wr[t]; swe[t] = We[t];
        sat[t] = att[t]; sbs[t] = bl[t] + br[t];
    }
    for (int i = t; i < nbuck; i += 256)
        cursor[i] = base[i] + off[(size_t)i * nblk + b];
    __syncthreads();

    int start = b * CHUNK;
    for (int u = 0; u < CHUNK / 256; ++u) {
        int e = start + u * 256 + t;
        if (e >= E) break;                 // e increases with u per thread
        int src = ei[e], dst = ei[E + e];
        float xs = x[src], xd = x[dst], a = ea[e];
        float l0 = 0.f, l1 = 0.f;
        #pragma unroll
        for (int c = 0; c < CDIM; ++c) {
            float v = fmaf(xs, swl[c], fmaf(xd, swr[c], fmaf(a, swe[c], sbs[c])));
            v = v > 0.f ? v : 0.2f * v;
            l0 = fmaf(v, sat[c], l0);
        }
        #pragma unroll
        for (int c = CDIM; c < HC; ++c) {
            float v = fmaf(xs, swl[c], fmaf(xd, swr[c], fmaf(a, swe[c], sbs[c])));
            v = v > 0.f ? v : 0.2f * v;
            l1 = fmaf(v, sat[c], l1);
        }
        float ex0 = __expf(l0), ex1 = __expf(l1);
        float w = xs + KOFF;               // > 0
        unsigned d0 = (unsigned)(ex0 * 65536.0f + 0.5f);
        unsigned n0 = (unsigned)(ex0 * w * 1048576.0f + 0.5f);
        unsigned d1 = (unsigned)(ex1 * 65536.0f + 0.5f);
        unsigned n1 = (unsigned)(ex1 * w * 1048576.0f + 0.5f);
        unsigned bk = ((unsigned)dst) >> BSH;
        unsigned pos = atomicAdd(&cursor[bk], 1u);   // LDS atomic (fast)
        payA[pos] = make_uint4(d0, n0, d1, n1);
        payD[pos] = (unsigned)dst & (BNODES - 1);
    }
}

// ---------------------------------------------------------------------------
// Pass 4: one block per bucket; LDS u32 accumulators (4 fields x 128 nodes),
// contiguous payload reads, exact integer sums; write packed u64 accP.
// ---------------------------------------------------------------------------
__global__ __launch_bounds__(256) void accum_kernel(
    const uint4* __restrict__ payA, const unsigned* __restrict__ payD,
    const unsigned* __restrict__ base, const unsigned* __restrict__ totals,
    unsigned long long* __restrict__ accP, int N)
{
    __shared__ unsigned acc4[BNODES][4];
    int t = threadIdx.x, bk = blockIdx.x;
    if (t < BNODES) { acc4[t][0] = 0; acc4[t][1] = 0; acc4[t][2] = 0; acc4[t][3] = 0; }
    __syncthreads();
    unsigned b0 = base[bk], tot = totals[bk];
    for (unsigned i = t; i < tot; i += 256) {
        uint4 p = payA[b0 + i];
        unsigned d = payD[b0 + i];
        atomicAdd(&acc4[d][0], p.x);
        atomicAdd(&acc4[d][1], p.y);
        atomicAdd(&acc4[d][2], p.z);
        atomicAdd(&acc4[d][3], p.w);
    }
    __syncthreads();
    if (t < BNODES) {
        int node = bk * BNODES + t;
        if (node < N) {
            accP[node * 2 + 0] = ((unsigned long long)acc4[t][0] << 32) | acc4[t][1];
            accP[node * 2 + 1] = ((unsigned long long)acc4[t][2] << 32) | acc4[t][3];
        }
    }
}

// ---------------------------------------------------------------------------
// me_y: me[b] = fc_b + fcW . msg[b], reduced to the FIVE rank factors:
//   y[0]=<Wl[0:64],me> y[1]=<Wl[64:128],me> y[2]=<bl[0:64],me>
//   y[3]=<bl[64:128],me> y[4]=<bias_out,me>   (exact rank-5 factorization)
// ---------------------------------------------------------------------------
__global__ __launch_bounds__(128) void me_y_kernel(
    const float* __restrict__ message, const float* __restrict__ fcW,
    const float* __restrict__ fcb,
    const float* __restrict__ Wl, const float* __restrict__ bl,
    const float* __restrict__ bias_out,
    float* __restrict__ y)              // [5][BCOLS]
{
    __shared__ float msg[HID];
    __shared__ float part[3][2];
    int b = blockIdx.x, t = threadIdx.x;
    msg[t]       = message[b * HID + t];
    msg[t + 128] = message[b * HID + 128 + t];
    __syncthreads();
    float acc = fcb[t];
    const float4* w4 = (const float4*)(fcW + t * HID);
    const float4* m4 = (const float4*)msg;
    #pragma unroll
    for (int q = 0; q < HID / 4; ++q) {
        float4 w = w4[q], m = m4[q];
        acc = fmaf(w.x, m.x, fmaf(w.y, m.y, fmaf(w.z, m.z, fmaf(w.w, m.w, acc))));
    }
    float p0 = Wl[t] * acc, p1 = bl[t] * acc, p2 = bias_out[t] * acc;
    #pragma unroll
    for (int d = 1; d < 64; d <<= 1) {
        p0 += __shfl_xor(p0, d); p1 += __shfl_xor(p1, d); p2 += __shfl_xor(p2, d);
    }
    int wv = t >> 6;
    if ((t & 63) == 0) { part[0][wv] = p0; part[1][wv] = p1; part[2][wv] = p2; }
    __syncthreads();
    if (t == 0) {
        y[0 * BCOLS + b] = part[0][0];
        y[1 * BCOLS + b] = part[0][1];
        y[2 * BCOLS + b] = part[1][0];
        y[3 * BCOLS + b] = part[1][1];
        y[4 * BCOLS + b] = part[2][0] + part[2][1];
    }
}

// ---------------------------------------------------------------------------
// row_softmax: decode (S,T), rank-5 logits, exp, wave-reduce, write probs.
// ---------------------------------------------------------------------------
__global__ __launch_bounds__(256) void row_softmax_kernel(
    const unsigned long long* __restrict__ accP,   // [N][2]
    const float* __restrict__ y,                   // [5][BCOLS]
    float* __restrict__ out, int N)
{
    __shared__ float ys[5][BCOLS];      // 20 KB
    int t = threadIdx.x;
    for (int r = t; r < 5 * BCOLS; r += 256)
        ((float*)ys)[r] = y[r];
    __syncthreads();

    int wv = t >> 6, ln = t & 63;
    int node = blockIdx.x * 4 + wv;
    if (node >= N) return;

    unsigned long long v0 = accP[node * 2 + 0];
    unsigned long long v1 = accP[node * 2 + 1];
    float S0 = 0.f, T0 = 0.f, S1 = 0.f, T1 = 0.f;
    if (v0 != 0ULL) {
        double den  = (double)(v0 >> 32) * (1.0 / 65536.0);
        double nump = (double)(v0 & 0xffffffffULL) * (1.0 / 1048576.0);
        S0 = (float)((nump - (double)KOFF * den) / den);
        T0 = (float)(den / (den + 1e-16));
    }
    if (v1 != 0ULL) {
        double den  = (double)(v1 >> 32) * (1.0 / 65536.0);
        double nump = (double)(v1 & 0xffffffffULL) * (1.0 / 1048576.0);
        S1 = (float)((nump - (double)KOFF * den) / den);
        T1 = (float)(den / (den + 1e-16));
    }

    float e[16];
    float sum = 0.f;
    #pragma unroll
    for (int u = 0; u < 4; ++u) {
        int c = ln * 4 + u * 256;
        float4 a  = *(const float4*)&ys[0][c];
        float4 b2 = *(const float4*)&ys[1][c];
        float4 c2 = *(const float4*)&ys[2][c];
        float4 d2 = *(const float4*)&ys[3][c];
        float4 k2 = *(const float4*)&ys[4][c];
        float lx = fmaf(S0, a.x, fmaf(S1, b2.x, fmaf(T0, c2.x, fmaf(T1, d2.x, k2.x))));
        float ly = fmaf(S0, a.y, fmaf(S1, b2.y, fmaf(T0, c2.y, fmaf(T1, d2.y, k2.y))));
        float lz = fmaf(S0, a.z, fmaf(S1, b2.z, fmaf(T0, c2.z, fmaf(T1, d2.z, k2.z))));
        float lw = fmaf(S0, a.w, fmaf(S1, b2.w, fmaf(T0, c2.w, fmaf(T1, d2.w, k2.w))));
        e[u * 4 + 0] = __expf(lx); e[u * 4 + 1] = __expf(ly);
        e[u * 4 + 2] = __expf(lz); e[u * 4 + 3] = __expf(lw);
        sum += e[u * 4 + 0] + e[u * 4 + 1] + e[u * 4 + 2] + e[u * 4 + 3];
    }
    #pragma unroll
    for (int d = 1; d < 64; d <<= 1) sum += __shfl_xor(sum, d);
    float inv = 1.f / sum;

    float* orow = out + (size_t)node * BCOLS;
    #pragma unroll
    for (int u = 0; u < 4; ++u) {
        float4 o = make_float4(e[u * 4 + 0] * inv, e[u * 4 + 1] * inv,
                               e[u * 4 + 2] * inv, e[u * 4 + 3] * inv);
        *(float4*)(orow + ln * 4 + u * 256) = o;
    }
}

extern "C" void kernel_launch(void* const* d_in, const int* in_sizes, int n_in,
                              void* d_out, int out_size, void* d_ws, size_t ws_size,
                              hipStream_t stream) {
    const float* x        = (const float*)d_in[0];
    const int*   ei       = (const int*)d_in[1];
    const float* ea       = (const float*)d_in[2];
    const float* message  = (const float*)d_in[3];
    const float* Wl       = (const float*)d_in[4];
    const float* bl       = (const float*)d_in[5];
    const float* Wr       = (const float*)d_in[6];
    const float* br       = (const float*)d_in[7];
    const float* We       = (const float*)d_in[8];
    const float* att      = (const float*)d_in[9];
    const float* bias_out = (const float*)d_in[10];
    const float* fcW      = (const float*)d_in[11];
    const float* fcb      = (const float*)d_in[12];

    int N = in_sizes[0];          // 50000
    int E = in_sizes[2];          // 1600000
    int B = in_sizes[3] / HID;    // 1024
    int nblk  = (E + CHUNK - 1) / CHUNK;      // 782
    int nbuck = (N + BNODES - 1) / BNODES;    // 391  (<= MAXBUCK)

    // ws: accP u64[N*2] (800 KB) + y f32[5*BCOLS] (20 KB)
    unsigned long long* accP = (unsigned long long*)d_ws;
    float* y = (float*)(accP + (size_t)N * 2);

    // d_out doubles as sort scratch (~35 MB of 205 MB); fully overwritten
    // by row_softmax at the end of every call.
    char* ob = (char*)d_out;
    uint4*    payA   = (uint4*)ob;                                  // E*16 B
    unsigned* payD   = (unsigned*)(ob + (size_t)E * 16);            // E*4 B
    unsigned* counts = (unsigned*)(ob + (size_t)E * 20);            // nbuck*nblk*4
    unsigned* off    = counts + (size_t)nbuck * nblk;               // nbuck*nblk*4
    unsigned* totals = off + (size_t)nbuck * nblk;                  // nbuck*4
    unsigned* basep  = totals + nbuck;                              // nbuck*4

    me_y_kernel<<<B, 128, 0, stream>>>(message, fcW, fcb, Wl, bl, bias_out, y);
    count_kernel<<<nblk, 256, 0, stream>>>(ei, counts, E, nblk, nbuck);
    scan_bucket_kernel<<<nbuck, 64, 0, stream>>>(counts, off, totals, nblk);
    scan_base_kernel<<<1, 64, 0, stream>>>(totals, basep, nbuck);
    scatter_kernel<<<nblk, 256, 0, stream>>>(x, ei, ea, Wl, bl, Wr, br, We, att,
                                             off, basep, payA, payD, E, nblk, nbuck);
    accum_kernel<<<nbuck, 256, 0, stream>>>(payA, payD, basep, totals, accP, N);
    row_softmax_kernel<<<(N + 3) / 4, 256, 0, stream>>>(accP, y, (float*)d_out, N);
}